// Round 2
// baseline (559.575 us; speedup 1.0000x reference)
//
#include <hip/hip_runtime.h>
#include <stdint.h>

typedef unsigned short u16;
typedef unsigned int u32;
typedef float f32x4 __attribute__((ext_vector_type(4)));
typedef int   i32x4 __attribute__((ext_vector_type(4)));
typedef __bf16 bf16x8 __attribute__((ext_vector_type(8)));

constexpr int S_LEN = 4096;
constexpr int HID   = 2048;
constexpr int WIN   = 2048;

__device__ __forceinline__ u32 f2bf_u(float f) {
  u32 u = __builtin_bit_cast(u32, f);
  return (u + 0x7fffu + ((u >> 16) & 1u)) >> 16;
}
__device__ __forceinline__ float bf2f(u16 u) {
  return __builtin_bit_cast(float, ((u32)u) << 16);
}
__device__ __forceinline__ void mfma16(f32x4& acc, i32x4 a, i32x4 b) {
  acc = __builtin_amdgcn_mfma_f32_16x16x32_bf16(
      __builtin_bit_cast(bf16x8, a), __builtin_bit_cast(bf16x8, b), acc, 0, 0, 0);
}
__device__ __forceinline__ void gload_lds16(const u16* g, u16* l) {
  __builtin_amdgcn_global_load_lds((const __attribute__((address_space(1))) u32*)g,
                                   (__attribute__((address_space(3))) u32*)l, 16, 0, 0);
}

// ---------------- fp32 -> bf16 convert (8 elems/thread) ----------------
__global__ __launch_bounds__(256) void cvt_bf16_kernel(const float* __restrict__ src,
                                                       u16* __restrict__ dst, int n8) {
  int t = blockIdx.x * 256 + threadIdx.x;
  if (t >= n8) return;
  const f32x4* s = (const f32x4*)src + (size_t)t * 2;
  f32x4 a = s[0], b = s[1];
  i32x4 o;
  o.x = (int)(f2bf_u(a.x) | (f2bf_u(a.y) << 16));
  o.y = (int)(f2bf_u(a.z) | (f2bf_u(a.w) << 16));
  o.z = (int)(f2bf_u(b.x) | (f2bf_u(b.y) << 16));
  o.w = (int)(f2bf_u(b.z) | (f2bf_u(b.w) << 16));
  *((i32x4*)dst + t) = o;
}

// ---------------- RoPE cos/sin table: [S][64] each ----------------
__global__ __launch_bounds__(256) void rope_table_kernel(float* __restrict__ cs,
                                                         float* __restrict__ sn) {
  int t = blockIdx.x * 256 + threadIdx.x;  // S*64 threads
  int d = t & 63, s = t >> 6;
  // inv_freq = 10000^(-2d/128) = 2^(-d * log2(10000)/64)
  float inv = exp2f(-(float)d * 0.20762050593046014f);
  float f = (float)s * inv;
  cs[t] = cosf(f);
  sn[t] = sinf(f);
}

// ---------------- in-place RoPE on [S][NH*128] bf16 ----------------
template <int NH>
__global__ __launch_bounds__(256) void rope_apply_kernel(u16* __restrict__ X,
                                                         const float* __restrict__ cs,
                                                         const float* __restrict__ sn) {
  int t = blockIdx.x * 256 + threadIdx.x;  // S*NH*64 threads
  int d = t & 63;
  int r = t >> 6;
  int h = r % NH;
  int s = r / NH;
  float c = cs[(s << 6) | d], si = sn[(s << 6) | d];
  u16* p = X + (size_t)s * (NH * 128) + h * 128 + d;
  float x1 = bf2f(p[0]), x2 = bf2f(p[64]);
  p[0]  = (u16)f2bf_u(x1 * c - x2 * si);
  p[64] = (u16)f2bf_u(x2 * c + x1 * si);
}

// ---------------- GEMM: C[M][N] = A[M][K] * B[N][K]^T, bf16 in, fp32 acc ----
// OUT_MODE 0: bf16 C[row*N+col]; 1: bf16 transposed C[col*S_LEN+row]; 2: fp32 C
template <int OUT_MODE>
__global__ __launch_bounds__(256) void gemm_bt_kernel(const u16* __restrict__ A,
                                                      const u16* __restrict__ B,
                                                      void* __restrict__ Cv,
                                                      int K, int N) {
  __shared__ __attribute__((aligned(16))) u16 sA[128 * 64];
  __shared__ __attribute__((aligned(16))) u16 sB[128 * 64];
  const int lane = threadIdx.x & 63;
  const int w = threadIdx.x >> 6;
  const int g = lane >> 4, ln = lane & 15;
  const int brow = blockIdx.y * 128;
  const int bcol = blockIdx.x * 128;
  const int wr = (w >> 1) * 64, wc = (w & 1) * 64;

  f32x4 acc[4][4] = {};

  // staging geometry: per issue i: row = w*32 + i*8 + lane/8, col = (lane%8)*8
  const int sr = w * 32 + (lane >> 3);
  const int scol = (lane & 7) * 8;
  const u16* Abase = A + (size_t)(brow + sr) * K + scol;
  const u16* Bbase = B + (size_t)(bcol + sr) * K + scol;
  u16* sAdst = &sA[w * 2048];
  u16* sBdst = &sB[w * 2048];

  for (int k0 = 0; k0 < K; k0 += 64) {
    __syncthreads();
#pragma unroll
    for (int i = 0; i < 4; ++i) {
      gload_lds16(Abase + (size_t)i * 8 * K + k0, sAdst + i * 512);
      gload_lds16(Bbase + (size_t)i * 8 * K + k0, sBdst + i * 512);
    }
    __syncthreads();
#pragma unroll
    for (int kk = 0; kk < 2; ++kk) {
      i32x4 af[4], bfr[4];
#pragma unroll
      for (int m = 0; m < 4; ++m)
        af[m] = *(const i32x4*)&sA[(wr + m * 16 + ln) * 64 + kk * 32 + g * 8];
#pragma unroll
      for (int n = 0; n < 4; ++n)
        bfr[n] = *(const i32x4*)&sB[(wc + n * 16 + ln) * 64 + kk * 32 + g * 8];
#pragma unroll
      for (int m = 0; m < 4; ++m)
#pragma unroll
        for (int n = 0; n < 4; ++n) mfma16(acc[m][n], af[m], bfr[n]);
    }
  }

  const int orow0 = brow + wr + g * 4;
  const int ocol0 = bcol + wc + ln;
#pragma unroll
  for (int m = 0; m < 4; ++m)
#pragma unroll
    for (int n = 0; n < 4; ++n)
#pragma unroll
      for (int j = 0; j < 4; ++j) {
        int row = orow0 + m * 16 + j;
        int col = ocol0 + n * 16;
        float v = acc[m][n][j];
        if constexpr (OUT_MODE == 0)
          ((u16*)Cv)[(size_t)row * N + col] = (u16)f2bf_u(v);
        else if constexpr (OUT_MODE == 1)
          ((u16*)Cv)[(size_t)col * S_LEN + row] = (u16)f2bf_u(v);
        else
          ((float*)Cv)[(size_t)row * N + col] = v;
      }
}

// ---------------- flash attention, sliding window, GQA ----------------
// grid: (64 q-tiles, 16 heads); block 256 = 4 waves x 16 q-rows
__global__ __launch_bounds__(256) void attn_kernel(const u16* __restrict__ Q,
                                                   const u16* __restrict__ Kb,
                                                   const u16* __restrict__ Vt,
                                                   u16* __restrict__ AO) {
  __shared__ __attribute__((aligned(16))) u16 sK[32 * 128];
  __shared__ __attribute__((aligned(16))) u16 sV[128 * 32];
  __shared__ __attribute__((aligned(16))) u16 sP[4][16 * 32];

  const int lane = threadIdx.x & 63;
  const int w = threadIdx.x >> 6;
  const int g = lane >> 4, ln = lane & 15;
  const int qt = 63 - blockIdx.x;  // heavy tiles first
  const int h = blockIdx.y;
  const int kvh = h >> 2;
  const int qb = qt * 64;
  const int qr0 = qb + w * 16;

  // Q fragments: rows qr0+ln, k-chunks c*32 + g*8
  i32x4 aq[4];
  {
    const u16* qp = Q + (size_t)(qr0 + ln) * HID + h * 128 + g * 8;
#pragma unroll
    for (int c = 0; c < 4; ++c) aq[c] = *(const i32x4*)(qp + c * 32);
  }

  f32x4 oacc[8] = {};
  float mrun[4] = {-1e30f, -1e30f, -1e30f, -1e30f};
  float lrun[4] = {0.f, 0.f, 0.f, 0.f};

  int lo = qb - (WIN - 1);
  if (lo < 0) lo = 0;
  lo &= ~31;
  const int hi = qb + 64;

  // staging geometry
  const int ksr = w * 8 + (lane >> 4);   // + i*4
  const int ksc = ln * 8;
  const int vsr = w * 32 + (lane >> 2);  // + i*16
  const int vsc = (lane & 3) * 8;
  const u16* Kbase = Kb + kvh * 128 + ksc;
  const u16* Vbase = Vt + (size_t)kvh * 128 * S_LEN + (size_t)vsr * S_LEN + vsc;
  u16* sKdst = &sK[w * 1024];
  u16* sVdst = &sV[w * 1024];

  const float scale = 0.088388347648318447f;  // 1/sqrt(128)

  for (int kb = lo; kb < hi; kb += 32) {
    __syncthreads();
#pragma unroll
    for (int i = 0; i < 2; ++i) {
      gload_lds16(Kbase + (size_t)(kb + ksr + i * 4) * 512, sKdst + i * 512);
      gload_lds16(Vbase + (size_t)i * 16 * S_LEN + kb, sVdst + i * 512);
    }
    __syncthreads();

    // wave-level skip: all rows of this wave masked?
    if (kb > qr0 + 15 || kb + 31 < qr0 - (WIN - 1)) continue;

    // S = Q K^T : 16 q x 32 k
    f32x4 sc0 = {}, sc1 = {};
#pragma unroll
    for (int c = 0; c < 4; ++c) {
      i32x4 b0 = *(const i32x4*)&sK[ln * 128 + c * 32 + g * 8];
      i32x4 b1 = *(const i32x4*)&sK[(16 + ln) * 128 + c * 32 + g * 8];
      mfma16(sc0, aq[c], b0);
      mfma16(sc1, aq[c], b1);
    }

    // mask + online softmax (rows qr0 + g*4 + j; cols kb + {ln, 16+ln})
    float p0[4], p1[4], corr[4];
#pragma unroll
    for (int j = 0; j < 4; ++j) {
      int qa = qr0 + g * 4 + j;
      int k0a = kb + ln, k1a = kb + 16 + ln;
      float s0 = (k0a <= qa && qa - k0a < WIN) ? sc0[j] * scale : -__builtin_inff();
      float s1 = (k1a <= qa && qa - k1a < WIN) ? sc1[j] * scale : -__builtin_inff();
      float mx = fmaxf(s0, s1);
#pragma unroll
      for (int off = 1; off < 16; off <<= 1) mx = fmaxf(mx, __shfl_xor(mx, off));
      float mnew = fmaxf(mrun[j], mx);
      p0[j] = __expf(s0 - mnew);
      p1[j] = __expf(s1 - mnew);
      corr[j] = __expf(mrun[j] - mnew);
      float rs = p0[j] + p1[j];
#pragma unroll
      for (int off = 1; off < 16; off <<= 1) rs += __shfl_xor(rs, off);
      lrun[j] = lrun[j] * corr[j] + rs;
      mrun[j] = mnew;
    }

    // stage P (bf16) to per-wave LDS, re-layout for PV
#pragma unroll
    for (int j = 0; j < 4; ++j) {
      sP[w][(g * 4 + j) * 32 + ln] = (u16)f2bf_u(p0[j]);
      sP[w][(g * 4 + j) * 32 + 16 + ln] = (u16)f2bf_u(p1[j]);
    }
#pragma unroll
    for (int nf = 0; nf < 8; ++nf)
#pragma unroll
      for (int j = 0; j < 4; ++j) oacc[nf][j] *= corr[j];

    i32x4 pa;
    __builtin_memcpy(&pa, &sP[w][ln * 32 + g * 8], 16);  // keeps write->read order
#pragma unroll
    for (int nf = 0; nf < 8; ++nf) {
      i32x4 bv = *(const i32x4*)&sV[(nf * 16 + ln) * 32 + g * 8];
      mfma16(oacc[nf], pa, bv);
    }
  }

  // epilogue: AO[q][h*128 + d]
  u16* aop = AO + (size_t)(qr0 + g * 4) * HID + h * 128 + ln;
#pragma unroll
  for (int j = 0; j < 4; ++j) {
    float inv = 1.f / lrun[j];
#pragma unroll
    for (int nf = 0; nf < 8; ++nf)
      aop[(size_t)j * HID + nf * 16] = (u16)f2bf_u(oacc[nf][j] * inv);
  }
}

// ---------------- orchestration ----------------
extern "C" void kernel_launch(void* const* d_in, const int* in_sizes, int n_in,
                              void* d_out, int out_size, void* d_ws, size_t ws_size,
                              hipStream_t stream) {
  const float* hx = (const float*)d_in[0];
  const float* qw = (const float*)d_in[1];
  const float* kw = (const float*)d_in[2];
  const float* vw = (const float*)d_in[3];
  const float* ow = (const float*)d_in[4];

  char* p = (char*)d_ws;
  u16* Xb = (u16*)p; p += (size_t)S_LEN * HID * 2;
  u16* Wq = (u16*)p; p += (size_t)HID * HID * 2;
  u16* Wk = (u16*)p; p += (size_t)512 * HID * 2;
  u16* Wv = (u16*)p; p += (size_t)512 * HID * 2;
  u16* Wo = (u16*)p; p += (size_t)HID * HID * 2;
  u16* Qb = (u16*)p; p += (size_t)S_LEN * HID * 2;
  u16* Kb = (u16*)p; p += (size_t)S_LEN * 512 * 2;
  u16* Vt = (u16*)p; p += (size_t)S_LEN * 512 * 2;
  u16* AO = (u16*)p; p += (size_t)S_LEN * HID * 2;
  float* cs = (float*)p; p += (size_t)S_LEN * 64 * 4;
  float* sn = (float*)p; p += (size_t)S_LEN * 64 * 4;

  cvt_bf16_kernel<<<4096, 256, 0, stream>>>(hx, Xb, S_LEN * HID / 8);
  cvt_bf16_kernel<<<2048, 256, 0, stream>>>(qw, Wq, HID * HID / 8);
  cvt_bf16_kernel<<<512, 256, 0, stream>>>(kw, Wk, 512 * HID / 8);
  cvt_bf16_kernel<<<512, 256, 0, stream>>>(vw, Wv, 512 * HID / 8);
  cvt_bf16_kernel<<<2048, 256, 0, stream>>>(ow, Wo, HID * HID / 8);
  rope_table_kernel<<<S_LEN * 64 / 256, 256, 0, stream>>>(cs, sn);

  gemm_bt_kernel<0><<<dim3(16, 32), 256, 0, stream>>>(Xb, Wq, Qb, HID, HID);
  gemm_bt_kernel<0><<<dim3(4, 32), 256, 0, stream>>>(Xb, Wk, Kb, HID, 512);
  gemm_bt_kernel<1><<<dim3(4, 32), 256, 0, stream>>>(Xb, Wv, Vt, HID, 512);

  rope_apply_kernel<16><<<S_LEN * 16 * 64 / 256, 256, 0, stream>>>(Qb, cs, sn);
  rope_apply_kernel<4><<<S_LEN * 4 * 64 / 256, 256, 0, stream>>>(Kb, cs, sn);

  attn_kernel<<<dim3(64, 16), 256, 0, stream>>>(Qb, Kb, Vt, AO);

  gemm_bt_kernel<2><<<dim3(16, 32), 256, 0, stream>>>(AO, Wo, d_out, HID, HID);
}

// Round 3
// 392.089 us; speedup vs baseline: 1.4272x; 1.4272x over previous
//
#include <hip/hip_runtime.h>
#include <stdint.h>

typedef unsigned short u16;
typedef unsigned int u32;
typedef float f32x4 __attribute__((ext_vector_type(4)));
typedef int   i32x4 __attribute__((ext_vector_type(4)));
typedef __bf16 bf16x8 __attribute__((ext_vector_type(8)));

constexpr int S_LEN = 4096;
constexpr int HID   = 2048;
constexpr int WIN   = 2048;

__device__ __forceinline__ u32 f2bf_u(float f) {
  u32 u = __builtin_bit_cast(u32, f);
  return (u + 0x7fffu + ((u >> 16) & 1u)) >> 16;
}
__device__ __forceinline__ float bf2f(u16 u) {
  return __builtin_bit_cast(float, ((u32)u) << 16);
}
__device__ __forceinline__ void mfma16(f32x4& acc, i32x4 a, i32x4 b) {
  acc = __builtin_amdgcn_mfma_f32_16x16x32_bf16(
      __builtin_bit_cast(bf16x8, a), __builtin_bit_cast(bf16x8, b), acc, 0, 0, 0);
}
__device__ __forceinline__ void gload_lds16(const u16* g, u16* l) {
  __builtin_amdgcn_global_load_lds((const __attribute__((address_space(1))) u32*)g,
                                   (__attribute__((address_space(3))) u32*)l, 16, 0, 0);
}

// ---------------- fp32 -> bf16 convert (8 elems/thread) ----------------
__global__ __launch_bounds__(256) void cvt_bf16_kernel(const float* __restrict__ src,
                                                       u16* __restrict__ dst, int n8) {
  int t = blockIdx.x * 256 + threadIdx.x;
  if (t >= n8) return;
  const f32x4* s = (const f32x4*)src + (size_t)t * 2;
  f32x4 a = s[0], b = s[1];
  i32x4 o;
  o.x = (int)(f2bf_u(a.x) | (f2bf_u(a.y) << 16));
  o.y = (int)(f2bf_u(a.z) | (f2bf_u(a.w) << 16));
  o.z = (int)(f2bf_u(b.x) | (f2bf_u(b.y) << 16));
  o.w = (int)(f2bf_u(b.z) | (f2bf_u(b.w) << 16));
  *((i32x4*)dst + t) = o;
}

// ---------------- RoPE cos/sin table: [S][64] each ----------------
__global__ __launch_bounds__(256) void rope_table_kernel(float* __restrict__ cs,
                                                         float* __restrict__ sn) {
  int t = blockIdx.x * 256 + threadIdx.x;  // S*64 threads
  int d = t & 63, s = t >> 6;
  float inv = exp2f(-(float)d * 0.20762050593046014f);  // log2(10000)/64
  float f = (float)s * inv;
  cs[t] = cosf(f);
  sn[t] = sinf(f);
}

// ---------------- in-place RoPE on [S][NH*128] bf16 ----------------
template <int NH>
__global__ __launch_bounds__(256) void rope_apply_kernel(u16* __restrict__ X,
                                                         const float* __restrict__ cs,
                                                         const float* __restrict__ sn) {
  int t = blockIdx.x * 256 + threadIdx.x;  // S*NH*64 threads
  int d = t & 63;
  int r = t >> 6;
  int h = r % NH;
  int s = r / NH;
  float c = cs[(s << 6) | d], si = sn[(s << 6) | d];
  u16* p = X + (size_t)s * (NH * 128) + h * 128 + d;
  float x1 = bf2f(p[0]), x2 = bf2f(p[64]);
  p[0]  = (u16)f2bf_u(x1 * c - x2 * si);
  p[64] = (u16)f2bf_u(x2 * c + x1 * si);
}

// ---------------- GEMM: C[M][N] = A[M][K] * B[N][K]^T, bf16 in, fp32 acc ----
// OUT_MODE 0: bf16 C[row*N+col]
// OUT_MODE 1: V tiled layout for attention (see attn_kernel PV fragment)
// OUT_MODE 2: fp32 C[row*N+col]
template <int OUT_MODE>
__global__ __launch_bounds__(256) void gemm_bt_kernel(const u16* __restrict__ A,
                                                      const u16* __restrict__ B,
                                                      void* __restrict__ Cv,
                                                      int K, int N) {
  __shared__ __attribute__((aligned(16))) u16 sA[128 * 64];
  __shared__ __attribute__((aligned(16))) u16 sB[128 * 64];
  const int lane = threadIdx.x & 63;
  const int w = threadIdx.x >> 6;
  const int g = lane >> 4, ln = lane & 15;
  const int brow = blockIdx.y * 128;
  const int bcol = blockIdx.x * 128;
  const int wr = (w >> 1) * 64, wc = (w & 1) * 64;

  f32x4 acc[4][4] = {};

  const int sr = w * 32 + (lane >> 3);
  const int scol = (lane & 7) * 8;
  const u16* Abase = A + (size_t)(brow + sr) * K + scol;
  const u16* Bbase = B + (size_t)(bcol + sr) * K + scol;
  u16* sAdst = &sA[w * 2048];
  u16* sBdst = &sB[w * 2048];

  for (int k0 = 0; k0 < K; k0 += 64) {
    __syncthreads();
#pragma unroll
    for (int i = 0; i < 4; ++i) {
      gload_lds16(Abase + (size_t)i * 8 * K + k0, sAdst + i * 512);
      gload_lds16(Bbase + (size_t)i * 8 * K + k0, sBdst + i * 512);
    }
    __syncthreads();
#pragma unroll
    for (int kk = 0; kk < 2; ++kk) {
      i32x4 af[4], bfr[4];
#pragma unroll
      for (int m = 0; m < 4; ++m)
        af[m] = *(const i32x4*)&sA[(wr + m * 16 + ln) * 64 + kk * 32 + g * 8];
#pragma unroll
      for (int n = 0; n < 4; ++n)
        bfr[n] = *(const i32x4*)&sB[(wc + n * 16 + ln) * 64 + kk * 32 + g * 8];
#pragma unroll
      for (int m = 0; m < 4; ++m)
#pragma unroll
        for (int n = 0; n < 4; ++n) mfma16(acc[m][n], af[m], bfr[n]);
    }
  }

  const int orow0 = brow + wr + g * 4;
  const int ocol0 = bcol + wc + ln;
#pragma unroll
  for (int m = 0; m < 4; ++m)
#pragma unroll
    for (int n = 0; n < 4; ++n)
#pragma unroll
      for (int j = 0; j < 4; ++j) {
        int row = orow0 + m * 16 + j;
        int col = ocol0 + n * 16;
        float v = acc[m][n][j];
        if constexpr (OUT_MODE == 0) {
          ((u16*)Cv)[(size_t)row * N + col] = (u16)f2bf_u(v);
        } else if constexpr (OUT_MODE == 1) {
          // V tiled: row = s, col = kvh*128 + d
          int d = col & 127, kvh = col >> 7;
          int T = row >> 5, ks = row & 31;
          int t = ks >> 4, gg = (ks >> 2) & 3, e = (t << 2) | (ks & 3);
          size_t idx = (size_t)kvh * S_LEN * 128 + (size_t)T * 4096 +
                       (size_t)d * 32 + ((size_t)(gg ^ ((d >> 1) & 3)) << 3) + e;
          ((u16*)Cv)[idx] = (u16)f2bf_u(v);
        } else {
          ((float*)Cv)[(size_t)row * N + col] = v;
        }
      }
}

// ---------------- flash attention, sliding window, GQA ----------------
// grid: (64 q-tiles, 16 heads); block 256 = 4 waves x 16 q-rows
// Swapped QK^T: each lane owns q-row (=ln), 8 scores (k = t*16 + g*4 + j).
__global__ __launch_bounds__(256) void attn_kernel(const u16* __restrict__ Q,
                                                   const u16* __restrict__ Kb,
                                                   const u16* __restrict__ Vt,
                                                   u16* __restrict__ AO) {
  __shared__ __attribute__((aligned(16))) u16 sK[2][32 * 128];
  __shared__ __attribute__((aligned(16))) u16 sV[2][32 * 128];

  const int lane = threadIdx.x & 63;
  const int w = threadIdx.x >> 6;
  const int g = lane >> 4, ln = lane & 15;
  const int qt = 63 - blockIdx.x;  // heavy tiles first
  const int h = blockIdx.y;
  const int kvh = h >> 2;
  const int qb = qt * 64;
  const int qr0 = qb + w * 16;

  // Q fragments (B-operand): rows qr0+ln, d-chunks c*32 + g*8
  i32x4 aq[4];
  {
    const u16* qp = Q + (size_t)(qr0 + ln) * HID + h * 128 + g * 8;
#pragma unroll
    for (int c = 0; c < 4; ++c) aq[c] = *(const i32x4*)(qp + c * 32);
  }

  f32x4 oacc[8] = {};
  float mrun = -1e30f, lrun = 0.f;

  int lo = qb - (WIN - 1);
  if (lo < 0) lo = 0;
  lo &= ~31;
  const int hi = qb + 64;
  const int nt = (hi - lo) >> 5;

  const u16* Vbase = Vt + (size_t)kvh * S_LEN * 128;
  const float scale = 0.088388347648318447f;  // 1/sqrt(128)

#define STAGE(KB, BUF)                                                         \
  {                                                                            \
    const int _kb = (KB);                                                      \
    _Pragma("unroll") for (int i = 0; i < 2; ++i) {                            \
      const int i4g = i * 4 + g;                                               \
      gload_lds16(Kb + (size_t)(_kb + w * 8 + i4g) * 512 + kvh * 128 +         \
                      ((ln ^ i4g) << 3),                                       \
                  &sK[BUF][w * 1024 + i * 512]);                               \
      gload_lds16(Vbase + (size_t)(_kb >> 5) * 4096 + w * 1024 + i * 512 +     \
                      lane * 8,                                                \
                  &sV[BUF][w * 1024 + i * 512]);                               \
    }                                                                          \
  }

  int cur = 0;
  STAGE(lo, 0);
  __syncthreads();

  const int q = qr0 + ln;
  const int vbase_off = ln * 32 + ((g ^ ((ln >> 1) & 3)) << 3);

  for (int it = 0; it < nt; ++it) {
    const int kb = lo + it * 32;
    if (it + 1 < nt) STAGE(kb + 32, cur ^ 1);

    if (!(kb > qr0 + 15 || kb + 31 < qr0 - (WIN - 1))) {
      const u16* sk = sK[cur];
      const u16* sv = sV[cur];

      f32x4 sc0 = {}, sc1 = {};
#pragma unroll
      for (int c = 0; c < 4; ++c) {
        const int slot = (((c * 4 + g) ^ (ln & 7)) << 3);
        i32x4 k0 = *(const i32x4*)&sk[ln * 128 + slot];
        i32x4 k1 = *(const i32x4*)&sk[(16 + ln) * 128 + slot];
        mfma16(sc0, k0, aq[c]);
        mfma16(sc1, k1, aq[c]);
      }

      float p[8];
      const bool interior = (kb + 31 <= qr0) && (qr0 + 15 - kb < WIN);
      if (interior) {
#pragma unroll
        for (int j = 0; j < 4; ++j) {
          p[j] = sc0[j] * scale;
          p[4 + j] = sc1[j] * scale;
        }
      } else {
        const float NEG = -__builtin_inff();
#pragma unroll
        for (int t = 0; t < 2; ++t)
#pragma unroll
          for (int j = 0; j < 4; ++j) {
            int k = kb + t * 16 + g * 4 + j;
            float s = (t ? sc1[j] : sc0[j]) * scale;
            p[t * 4 + j] = (k <= q && q - k < WIN) ? s : NEG;
          }
      }

      float mx = fmaxf(fmaxf(fmaxf(p[0], p[1]), fmaxf(p[2], p[3])),
                       fmaxf(fmaxf(p[4], p[5]), fmaxf(p[6], p[7])));
      mx = fmaxf(mx, __shfl_xor(mx, 16));
      mx = fmaxf(mx, __shfl_xor(mx, 32));
      const float mnew = fmaxf(mrun, mx);
      const float corr = __expf(mrun - mnew);
      mrun = mnew;
#pragma unroll
      for (int e = 0; e < 8; ++e) p[e] = __expf(p[e] - mnew);
      float rs = ((p[0] + p[1]) + (p[2] + p[3])) + ((p[4] + p[5]) + (p[6] + p[7]));
      rs += __shfl_xor(rs, 16);
      rs += __shfl_xor(rs, 32);
      lrun = lrun * corr + rs;

      f32x4 cvec;
#pragma unroll
      for (int j = 0; j < 4; ++j) cvec[j] = __shfl(corr, g * 4 + j);
#pragma unroll
      for (int nf = 0; nf < 8; ++nf)
#pragma unroll
        for (int j = 0; j < 4; ++j) oacc[nf][j] *= cvec[j];

      i32x4 pa;
      pa.x = (int)(f2bf_u(p[0]) | (f2bf_u(p[1]) << 16));
      pa.y = (int)(f2bf_u(p[2]) | (f2bf_u(p[3]) << 16));
      pa.z = (int)(f2bf_u(p[4]) | (f2bf_u(p[5]) << 16));
      pa.w = (int)(f2bf_u(p[6]) | (f2bf_u(p[7]) << 16));

#pragma unroll
      for (int nf = 0; nf < 8; ++nf) {
        i32x4 vb = *(const i32x4*)&sv[vbase_off + nf * 512];
        mfma16(oacc[nf], pa, vb);
      }
    }
    __syncthreads();
    cur ^= 1;
  }
#undef STAGE

  f32x4 linv;
#pragma unroll
  for (int j = 0; j < 4; ++j) linv[j] = 1.f / __shfl(lrun, g * 4 + j);
  u16* aop = AO + (size_t)(qr0 + g * 4) * HID + h * 128 + ln;
#pragma unroll
  for (int j = 0; j < 4; ++j)
#pragma unroll
    for (int nf = 0; nf < 8; ++nf)
      aop[(size_t)j * HID + nf * 16] = (u16)f2bf_u(oacc[nf][j] * linv[j]);
}

// ---------------- orchestration ----------------
extern "C" void kernel_launch(void* const* d_in, const int* in_sizes, int n_in,
                              void* d_out, int out_size, void* d_ws, size_t ws_size,
                              hipStream_t stream) {
  const float* hx = (const float*)d_in[0];
  const float* qw = (const float*)d_in[1];
  const float* kw = (const float*)d_in[2];
  const float* vw = (const float*)d_in[3];
  const float* ow = (const float*)d_in[4];

  char* p = (char*)d_ws;
  u16* Xb = (u16*)p; p += (size_t)S_LEN * HID * 2;
  u16* Wq = (u16*)p; p += (size_t)HID * HID * 2;
  u16* Wk = (u16*)p; p += (size_t)512 * HID * 2;
  u16* Wv = (u16*)p; p += (size_t)512 * HID * 2;
  u16* Wo = (u16*)p; p += (size_t)HID * HID * 2;
  u16* Qb = (u16*)p; p += (size_t)S_LEN * HID * 2;
  u16* Kb = (u16*)p; p += (size_t)S_LEN * 512 * 2;
  u16* Vt = (u16*)p; p += (size_t)S_LEN * 512 * 2;
  u16* AO = (u16*)p; p += (size_t)S_LEN * HID * 2;
  float* cs = (float*)p; p += (size_t)S_LEN * 64 * 4;
  float* sn = (float*)p; p += (size_t)S_LEN * 64 * 4;

  cvt_bf16_kernel<<<4096, 256, 0, stream>>>(hx, Xb, S_LEN * HID / 8);
  cvt_bf16_kernel<<<2048, 256, 0, stream>>>(qw, Wq, HID * HID / 8);
  cvt_bf16_kernel<<<512, 256, 0, stream>>>(kw, Wk, 512 * HID / 8);
  cvt_bf16_kernel<<<512, 256, 0, stream>>>(vw, Wv, 512 * HID / 8);
  cvt_bf16_kernel<<<2048, 256, 0, stream>>>(ow, Wo, HID * HID / 8);
  rope_table_kernel<<<S_LEN * 64 / 256, 256, 0, stream>>>(cs, sn);

  gemm_bt_kernel<0><<<dim3(16, 32), 256, 0, stream>>>(Xb, Wq, Qb, HID, HID);
  gemm_bt_kernel<0><<<dim3(4, 32), 256, 0, stream>>>(Xb, Wk, Kb, HID, 512);
  gemm_bt_kernel<1><<<dim3(4, 32), 256, 0, stream>>>(Xb, Wv, Vt, HID, 512);

  rope_apply_kernel<16><<<S_LEN * 16 * 64 / 256, 256, 0, stream>>>(Qb, cs, sn);
  rope_apply_kernel<4><<<S_LEN * 4 * 64 / 256, 256, 0, stream>>>(Kb, cs, sn);

  attn_kernel<<<dim3(64, 16), 256, 0, stream>>>(Qb, Kb, Vt, AO);

  gemm_bt_kernel<2><<<dim3(16, 32), 256, 0, stream>>>(AO, Wo, d_out, HID, HID);
}